// Round 2
// baseline (191.154 us; speedup 1.0000x reference)
//
#include <hip/hip_runtime.h>

// B=8, L=512, D=512, H=8. Q/K GEMMs: M=4096, N=4096, K=512 (bf16 MFMA).
// V path restructured: out[b,h,e] = sum_g (y'[b,hg,:] @ Wv[:, g*512+e]) + sum_g c[b,h,g]*bv[g*512+e]
//   y'[b,hg,d] = sum_l p[b,l,h,g]*Xv[b,l,d] + 63.875*sum_l Xv[b,l,d];  c = pb + 63.875*512

using bf16x8 = __attribute__((ext_vector_type(8))) short;
using f32x4  = __attribute__((ext_vector_type(4))) float;

__device__ __forceinline__ unsigned short f2bf(float f) {
    union { float f; unsigned int u; } c; c.f = f;
    unsigned int u = c.u;
    u += 0x7FFFu + ((u >> 16) & 1u);   // RTNE
    return (unsigned short)(u >> 16);
}
__device__ __forceinline__ float bflo(unsigned int u) {
    union { unsigned int u; float f; } c; c.u = u << 16; return c.f;
}
__device__ __forceinline__ float bfhi(unsigned int u) {
    union { unsigned int u; float f; } c; c.u = u & 0xFFFF0000u; return c.f;
}

#define GLOAD16(gp, lp) __builtin_amdgcn_global_load_lds( \
    (const __attribute__((address_space(1))) unsigned int*)(gp), \
    (__attribute__((address_space(3))) unsigned int*)(lp), 16, 0, 0)

// ---------------- kernel 1: convert Xq, Xk (f32 -> bf16) ----------------------------
__global__ void convert_x(const float* __restrict__ x0, const float* __restrict__ x1,
                          unsigned short* __restrict__ o0, unsigned short* __restrict__ o1,
                          int n)
{
    const float* src = (blockIdx.z == 0) ? x0 : x1;
    unsigned short* dst = (blockIdx.z == 0) ? o0 : o1;
    int i = (blockIdx.x * blockDim.x + threadIdx.x) * 4;
    if (i < n) {
        float4 v = *(const float4*)(src + i);
        ushort4 o;
        o.x = f2bf(v.x); o.y = f2bf(v.y); o.z = f2bf(v.z); o.w = f2bf(v.w);
        *(ushort4*)(dst + i) = o;
    }
}

// ---------------- kernel 2: transpose-convert Wq, Wk (512x4096 f32 -> 4096x512 bf16) -
__global__ void transpose_w(const float* __restrict__ w0, const float* __restrict__ w1,
                            unsigned short* __restrict__ t0, unsigned short* __restrict__ t1)
{
    const float* W = (blockIdx.z == 0) ? w0 : w1;
    unsigned short* T = (blockIdx.z == 0) ? t0 : t1;
    __shared__ float tile[32][33];
    const int n0 = blockIdx.x * 32, k0 = blockIdx.y * 32;
    const int tx = threadIdx.x, ty = threadIdx.y;   // (32, 8)
    #pragma unroll
    for (int j = 0; j < 32; j += 8)
        tile[ty + j][tx] = W[(size_t)(k0 + ty + j) * 4096 + n0 + tx];
    __syncthreads();
    #pragma unroll
    for (int j = 0; j < 32; j += 8)
        T[(size_t)(n0 + ty + j) * 512 + k0 + tx] = f2bf(tile[tx][ty + j]);
}

// ---------------- kernel 3: bf16 GEMM C = A(4096x512) @ Wt(4096x512)^T + bias -------
__global__ __launch_bounds__(256) void gemm_bt(
    const unsigned short* __restrict__ a0, const unsigned short* __restrict__ a1,
    const unsigned short* __restrict__ w0, const unsigned short* __restrict__ w1,
    const float* __restrict__ b0, const float* __restrict__ b1,
    unsigned short* __restrict__ c0, unsigned short* __restrict__ c1)
{
    const unsigned short* A;  const unsigned short* Bt; const float* bias; unsigned short* C;
    if (blockIdx.z == 0) { A = a0; Bt = w0; bias = b0; C = c0; }
    else                 { A = a1; Bt = w1; bias = b1; C = c1; }

    __shared__ __align__(16) unsigned short As[128 * 64];
    __shared__ __align__(16) unsigned short Bs[128 * 64];

    const int tid  = threadIdx.x;
    const int lane = tid & 63;
    const int wid  = tid >> 6;
    const int wr = wid >> 1, wc = wid & 1;
    const int row0 = blockIdx.y * 128;
    const int n0   = blockIdx.x * 128;

    const int srow  = lane >> 3;             // row within 8-row chunk
    const int sgran = (lane & 7) ^ srow;     // inverse-swizzled global 16B granule

    f32x4 acc[4][4];
    #pragma unroll
    for (int i = 0; i < 4; ++i)
        #pragma unroll
        for (int j = 0; j < 4; ++j)
            acc[i][j] = (f32x4){0.f, 0.f, 0.f, 0.f};

    for (int kt = 0; kt < 8; ++kt) {
        const int k0 = kt * 64;
        #pragma unroll
        for (int i = 0; i < 4; ++i) {
            const int ch = wid * 4 + i;            // chunk 0..15
            const int trow = ch * 8 + srow;        // tile row 0..127
            GLOAD16(A  + (size_t)(row0 + trow) * 512 + k0 + sgran * 8, As + ch * 512);
            GLOAD16(Bt + (size_t)(n0   + trow) * 512 + k0 + sgran * 8, Bs + ch * 512);
        }
        __syncthreads();
        #pragma unroll
        for (int t = 0; t < 2; ++t) {
            const int kb = ((t * 4 + (lane >> 4)) ^ (lane & 7)) << 4;
            bf16x8 af[4], bfr[4];
            #pragma unroll
            for (int i = 0; i < 4; ++i) {
                const int ar = wr * 64 + i * 16 + (lane & 15);
                af[i]  = *(const bf16x8*)((const char*)As + ar * 128 + kb);
                const int br = wc * 64 + i * 16 + (lane & 15);
                bfr[i] = *(const bf16x8*)((const char*)Bs + br * 128 + kb);
            }
            #pragma unroll
            for (int i = 0; i < 4; ++i)
                #pragma unroll
                for (int j = 0; j < 4; ++j)
                    acc[i][j] = __builtin_amdgcn_mfma_f32_16x16x32_bf16(af[i], bfr[j], acc[i][j], 0, 0, 0);
        }
        __syncthreads();
    }

    #pragma unroll
    for (int j = 0; j < 4; ++j) {
        const int cg = n0 + wc * 64 + j * 16 + (lane & 15);
        const float bb = bias[cg];
        #pragma unroll
        for (int i = 0; i < 4; ++i) {
            const int r0 = row0 + wr * 64 + i * 16 + (lane >> 4) * 4;
            #pragma unroll
            for (int r = 0; r < 4; ++r)
                C[(size_t)(r0 + r) * 4096 + cg] = f2bf(acc[i][j][r] + bb);
        }
    }
}

// ---------------- kernel 4: per-(b,l) 8x8 scores + softmax -> P[r][h*8+g] -----------
__global__ __launch_bounds__(64) void scores(const unsigned short* __restrict__ Q,
                                             const unsigned short* __restrict__ K,
                                             float* __restrict__ P)
{
    __shared__ __align__(16) unsigned short qs[8 * 520];
    __shared__ __align__(16) unsigned short ks[8 * 520];
    const int r = blockIdx.x;        // b*512 + l
    const int lane = threadIdx.x;    // 64
    const unsigned short* qrow = Q + (size_t)r * 4096;
    const unsigned short* krow = K + (size_t)r * 4096;
    #pragma unroll
    for (int m = 0; m < 8; ++m) {
        *(uint4*)(&qs[m * 520 + lane * 8]) = *(const uint4*)(qrow + m * 512 + lane * 8);
        *(uint4*)(&ks[m * 520 + lane * 8]) = *(const uint4*)(krow + m * 512 + lane * 8);
    }
    __syncthreads();

    const int h = lane >> 3, g = lane & 7;
    const unsigned short* qh = &qs[h * 520];
    const unsigned short* kg = &ks[g * 520];
    float dot = 0.f;
    #pragma unroll 4
    for (int m = 0; m < 64; ++m) {
        uint4 qa = *(const uint4*)(qh + m * 8);
        uint4 ka = *(const uint4*)(kg + m * 8);
        dot += bflo(qa.x) * bflo(ka.x) + bfhi(qa.x) * bfhi(ka.x);
        dot += bflo(qa.y) * bflo(ka.y) + bfhi(qa.y) * bfhi(ka.y);
        dot += bflo(qa.z) * bflo(ka.z) + bfhi(qa.z) * bfhi(ka.z);
        dot += bflo(qa.w) * bflo(ka.w) + bfhi(qa.w) * bfhi(ka.w);
    }
    float s = dot * 0.04419417382415922f;   // 1/sqrt(512)
    float mx = s;
    mx = fmaxf(mx, __shfl_xor(mx, 1));
    mx = fmaxf(mx, __shfl_xor(mx, 2));
    mx = fmaxf(mx, __shfl_xor(mx, 4));
    float e = __expf(s - mx);
    float sm = e;
    sm += __shfl_xor(sm, 1);
    sm += __shfl_xor(sm, 2);
    sm += __shfl_xor(sm, 4);
    P[(size_t)r * 64 + lane] = e / sm;
}

// ---------------- kernel 5: pb[b,hg] = sum_l P[b,l,hg] -------------------------------
__global__ __launch_bounds__(256) void pbkern(const float* __restrict__ P,
                                              float* __restrict__ pb)
{
    __shared__ float red[256];
    const int b = blockIdx.x, tid = threadIdx.x;
    const int hg = tid & 63, q = tid >> 6;
    float s = 0.f;
    for (int l = 0; l < 128; ++l) s += P[((size_t)b * 512 + q * 128 + l) * 64 + hg];
    red[tid] = s;
    __syncthreads();
    if (q == 0) pb[b * 64 + hg] = red[hg] + red[64 + hg] + red[128 + hg] + red[192 + hg];
}

// ---------------- kernel 6: y'[b,hg,d] = sum_l P*Xv + 63.875*sum_l Xv ----------------
__global__ __launch_bounds__(256) void ykern(const float* __restrict__ P,
                                             const float* __restrict__ Xv,
                                             float* __restrict__ Y)
{
    __shared__ float Pl[64 * 64];
    __shared__ float Xl[64 * 128];
    __shared__ float xstmp[256];
    const int b = blockIdx.x, dt = blockIdx.y;
    const int tid = threadIdx.x;
    const int hgb = (tid & 15) * 4;
    const int db  = (tid >> 4) * 8;
    const int xcol = tid & 127, xhalf = tid >> 7;

    float acc[4][8];
    #pragma unroll
    for (int i = 0; i < 4; ++i)
        #pragma unroll
        for (int j = 0; j < 8; ++j) acc[i][j] = 0.f;
    float xs_acc = 0.f;

    for (int lc = 0; lc < 8; ++lc) {
        const float* Pg = P + ((size_t)b * 512 + lc * 64) * 64;
        #pragma unroll
        for (int i = 0; i < 16; ++i) Pl[i * 256 + tid] = Pg[i * 256 + tid];
        const float* Xg = Xv + ((size_t)b * 512 + lc * 64) * 512 + dt * 128;
        #pragma unroll
        for (int i = 0; i < 8; ++i) {
            int flat = i * 256 + tid;            // float4 index, 2048 total
            int r = flat >> 5, c4 = flat & 31;
            *(float4*)&Xl[r * 128 + c4 * 4] = *(const float4*)(Xg + (size_t)r * 512 + c4 * 4);
        }
        __syncthreads();
        for (int l = 0; l < 64; ++l) {
            float pv[4], xv[8];
            #pragma unroll
            for (int i = 0; i < 4; ++i) pv[i] = Pl[l * 64 + hgb + i];
            #pragma unroll
            for (int j = 0; j < 8; ++j) xv[j] = Xl[l * 128 + db + j];
            #pragma unroll
            for (int i = 0; i < 4; ++i)
                #pragma unroll
                for (int j = 0; j < 8; ++j) acc[i][j] += pv[i] * xv[j];
        }
        #pragma unroll
        for (int l = 0; l < 32; ++l) xs_acc += Xl[(xhalf * 32 + l) * 128 + xcol];
        __syncthreads();
    }
    xstmp[tid] = xs_acc;
    __syncthreads();
    #pragma unroll
    for (int i = 0; i < 4; ++i) {
        float* yrow = Y + ((size_t)b * 64 + hgb + i) * 512 + dt * 128;
        #pragma unroll
        for (int j = 0; j < 8; ++j)
            yrow[db + j] = acc[i][j] + 63.875f * (xstmp[db + j] + xstmp[128 + db + j]);
    }
}

// ---------------- kernel 7: partial[dc,b,h,e] = sum_g sum_{d in dc} y' * Wv ----------
__global__ __launch_bounds__(256) void vgemm(const float* __restrict__ Y,
                                             const float* __restrict__ Wv,
                                             float* __restrict__ partial)
{
    __shared__ float yl[64 * 32];
    const int b = blockIdx.x, dc = blockIdx.y;
    const int tid = threadIdx.x;
    #pragma unroll
    for (int i = 0; i < 8; ++i) {
        int flat = i * 256 + tid;                // 2048 = 64hg x 32d
        int hg = flat >> 5, j = flat & 31;
        yl[flat] = Y[((size_t)b * 64 + hg) * 512 + dc * 32 + j];
    }
    __syncthreads();
    const int h = tid >> 5;
    const int e0 = (tid & 31) * 16;
    float acc[16];
    #pragma unroll
    for (int q = 0; q < 16; ++q) acc[q] = 0.f;
    for (int d = 0; d < 32; ++d) {
        const float* wrow = Wv + (size_t)(dc * 32 + d) * 4096;
        #pragma unroll
        for (int g = 0; g < 8; ++g) {
            float yv = yl[(h * 8 + g) * 32 + d];
            const float4* w4 = (const float4*)(wrow + g * 512 + e0);
            #pragma unroll
            for (int q = 0; q < 4; ++q) {
                float4 w = w4[q];
                acc[q * 4 + 0] += yv * w.x; acc[q * 4 + 1] += yv * w.y;
                acc[q * 4 + 2] += yv * w.z; acc[q * 4 + 3] += yv * w.w;
            }
        }
    }
    float* op = partial + ((size_t)dc * 8 + b) * 4096 + h * 512 + e0;
    #pragma unroll
    for (int q = 0; q < 4; ++q)
        *(float4*)(op + q * 4) = make_float4(acc[q*4+0], acc[q*4+1], acc[q*4+2], acc[q*4+3]);
}

// ---------------- kernel 8: out = sum_dc partial + sum_g (pb+32704)*bv ---------------
__global__ void finalize(const float* __restrict__ partial, const float* __restrict__ pb,
                         const float* __restrict__ bv, float* __restrict__ out)
{
    int i = blockIdx.x * blockDim.x + threadIdx.x;  // 32768
    int b = i >> 12, h = (i >> 9) & 7, e = i & 511;
    float s = 0.f;
    #pragma unroll
    for (int dc = 0; dc < 16; ++dc) s += partial[((size_t)dc * 8 + b) * 4096 + h * 512 + e];
    float bt = 0.f;
    #pragma unroll
    for (int g = 0; g < 8; ++g) bt += (pb[b * 64 + h * 8 + g] + 32704.f) * bv[g * 512 + e];
    out[i] = s + bt;
}

extern "C" void kernel_launch(void* const* d_in, const int* in_sizes, int n_in,
                              void* d_out, int out_size, void* d_ws, size_t ws_size,
                              hipStream_t stream)
{
    const float* queries = (const float*)d_in[0];
    const float* keys    = (const float*)d_in[1];
    const float* values  = (const float*)d_in[2];
    const float* Wq      = (const float*)d_in[3];
    const float* bq      = (const float*)d_in[4];
    const float* Wk      = (const float*)d_in[5];
    const float* bk      = (const float*)d_in[6];
    // d_in[7] = Wv, d_in[8] = bv
    const float* Wv      = (const float*)d_in[7];
    const float* bv      = (const float*)d_in[8];

    unsigned short* xq  = (unsigned short*)d_ws;
    unsigned short* xk  = xq  + (1u << 21);
    unsigned short* wtq = xk  + (1u << 21);
    unsigned short* wtk = wtq + (1u << 21);
    unsigned short* Q   = wtk + (1u << 21);
    unsigned short* Kb  = Q   + (1u << 24);
    float* P    = (float*)(Kb + (1u << 24));
    float* pb   = P + 4096 * 64;
    float* Y    = pb + 512;
    float* part = Y + 8 * 64 * 512;

    convert_x<<<dim3(2048, 1, 2), 256, 0, stream>>>(queries, keys, xq, xk, 2097152);
    transpose_w<<<dim3(128, 16, 2), dim3(32, 8), 0, stream>>>(Wq, Wk, wtq, wtk);
    gemm_bt<<<dim3(32, 32, 2), 256, 0, stream>>>(xq, xk, wtq, wtk, bq, bk, Q, Kb);
    scores<<<dim3(4096), 64, 0, stream>>>(Q, Kb, P);
    pbkern<<<dim3(8), 256, 0, stream>>>(P, pb);
    ykern<<<dim3(8, 4), 256, 0, stream>>>(P, values, Y);
    vgemm<<<dim3(8, 16), 256, 0, stream>>>(Y, Wv, part);
    finalize<<<dim3(128), 256, 0, stream>>>(part, pb, bv, (float*)d_out);
}

// Round 3
// 109.946 us; speedup vs baseline: 1.7386x; 1.7386x over previous
//
#include <hip/hip_runtime.h>

// B=8, L=512, D=512, H=8. Q/K GEMMs: M=4096, N=4096, K=512 (bf16 MFMA).
// V path (all f32, no V projection GEMM):
//   P' = softmax + 63.875                                  (scores)
//   c[b,hg] = sum_l P'                                     (pbkern)
//   Y[b,hg,d] = sum_l P'[b,l,hg] * Xv[b,l,d]               (ykern x4 lc-partials + yreduce)
//   out[b,h,e] = sum_g Y[b,hg,:] @ Wv[:,g*512+e] + sum_g c[b,hg]*bv[g*512+e]
//              = split-K GEMM (M=64,N=512,K=4096) partials (vgemm) + finalize

using bf16x8 = __attribute__((ext_vector_type(8))) short;
using f32x4  = __attribute__((ext_vector_type(4))) float;

__device__ __forceinline__ unsigned short f2bf(float f) {
    union { float f; unsigned int u; } c; c.f = f;
    unsigned int u = c.u;
    u += 0x7FFFu + ((u >> 16) & 1u);   // RTNE
    return (unsigned short)(u >> 16);
}
__device__ __forceinline__ float bflo(unsigned int u) {
    union { unsigned int u; float f; } c; c.u = u << 16; return c.f;
}
__device__ __forceinline__ float bfhi(unsigned int u) {
    union { unsigned int u; float f; } c; c.u = u & 0xFFFF0000u; return c.f;
}

#define GLOAD16(gp, lp) __builtin_amdgcn_global_load_lds( \
    (const __attribute__((address_space(1))) unsigned int*)(gp), \
    (__attribute__((address_space(3))) unsigned int*)(lp), 16, 0, 0)

// ---------------- kernel 1: convert Xq, Xk (f32 -> bf16) ----------------------------
__global__ void convert_x(const float* __restrict__ x0, const float* __restrict__ x1,
                          unsigned short* __restrict__ o0, unsigned short* __restrict__ o1,
                          int n)
{
    const float* src = (blockIdx.z == 0) ? x0 : x1;
    unsigned short* dst = (blockIdx.z == 0) ? o0 : o1;
    int i = (blockIdx.x * blockDim.x + threadIdx.x) * 4;
    if (i < n) {
        float4 v = *(const float4*)(src + i);
        ushort4 o;
        o.x = f2bf(v.x); o.y = f2bf(v.y); o.z = f2bf(v.z); o.w = f2bf(v.w);
        *(ushort4*)(dst + i) = o;
    }
}

// ---------------- kernel 2: transpose-convert Wq, Wk (512x4096 f32 -> 4096x512 bf16) -
__global__ void transpose_w(const float* __restrict__ w0, const float* __restrict__ w1,
                            unsigned short* __restrict__ t0, unsigned short* __restrict__ t1)
{
    const float* W = (blockIdx.z == 0) ? w0 : w1;
    unsigned short* T = (blockIdx.z == 0) ? t0 : t1;
    __shared__ float tile[32][33];
    const int n0 = blockIdx.x * 32, k0 = blockIdx.y * 32;
    const int tx = threadIdx.x, ty = threadIdx.y;   // (32, 8)
    #pragma unroll
    for (int j = 0; j < 32; j += 8)
        tile[ty + j][tx] = W[(size_t)(k0 + ty + j) * 4096 + n0 + tx];
    __syncthreads();
    #pragma unroll
    for (int j = 0; j < 32; j += 8)
        T[(size_t)(n0 + ty + j) * 512 + k0 + tx] = f2bf(tile[tx][ty + j]);
}

// ---------------- kernel 3: bf16 GEMM C = A(4096x512) @ Wt(4096x512)^T + bias -------
__global__ __launch_bounds__(256) void gemm_bt(
    const unsigned short* __restrict__ a0, const unsigned short* __restrict__ a1,
    const unsigned short* __restrict__ w0, const unsigned short* __restrict__ w1,
    const float* __restrict__ b0, const float* __restrict__ b1,
    unsigned short* __restrict__ c0, unsigned short* __restrict__ c1)
{
    const unsigned short* A;  const unsigned short* Bt; const float* bias; unsigned short* C;
    if (blockIdx.z == 0) { A = a0; Bt = w0; bias = b0; C = c0; }
    else                 { A = a1; Bt = w1; bias = b1; C = c1; }

    __shared__ __align__(16) unsigned short As[128 * 64];
    __shared__ __align__(16) unsigned short Bs[128 * 64];

    const int tid  = threadIdx.x;
    const int lane = tid & 63;
    const int wid  = tid >> 6;
    const int wr = wid >> 1, wc = wid & 1;
    const int row0 = blockIdx.y * 128;
    const int n0   = blockIdx.x * 128;

    const int srow  = lane >> 3;
    const int sgran = (lane & 7) ^ srow;

    f32x4 acc[4][4];
    #pragma unroll
    for (int i = 0; i < 4; ++i)
        #pragma unroll
        for (int j = 0; j < 4; ++j)
            acc[i][j] = (f32x4){0.f, 0.f, 0.f, 0.f};

    for (int kt = 0; kt < 8; ++kt) {
        const int k0 = kt * 64;
        #pragma unroll
        for (int i = 0; i < 4; ++i) {
            const int ch = wid * 4 + i;
            const int trow = ch * 8 + srow;
            GLOAD16(A  + (size_t)(row0 + trow) * 512 + k0 + sgran * 8, As + ch * 512);
            GLOAD16(Bt + (size_t)(n0   + trow) * 512 + k0 + sgran * 8, Bs + ch * 512);
        }
        __syncthreads();
        #pragma unroll
        for (int t = 0; t < 2; ++t) {
            const int kb = ((t * 4 + (lane >> 4)) ^ (lane & 7)) << 4;
            bf16x8 af[4], bfr[4];
            #pragma unroll
            for (int i = 0; i < 4; ++i) {
                const int ar = wr * 64 + i * 16 + (lane & 15);
                af[i]  = *(const bf16x8*)((const char*)As + ar * 128 + kb);
                const int br = wc * 64 + i * 16 + (lane & 15);
                bfr[i] = *(const bf16x8*)((const char*)Bs + br * 128 + kb);
            }
            #pragma unroll
            for (int i = 0; i < 4; ++i)
                #pragma unroll
                for (int j = 0; j < 4; ++j)
                    acc[i][j] = __builtin_amdgcn_mfma_f32_16x16x32_bf16(af[i], bfr[j], acc[i][j], 0, 0, 0);
        }
        __syncthreads();
    }

    #pragma unroll
    for (int j = 0; j < 4; ++j) {
        const int cg = n0 + wc * 64 + j * 16 + (lane & 15);
        const float bb = bias[cg];
        #pragma unroll
        for (int i = 0; i < 4; ++i) {
            const int r0 = row0 + wr * 64 + i * 16 + (lane >> 4) * 4;
            #pragma unroll
            for (int r = 0; r < 4; ++r)
                C[(size_t)(r0 + r) * 4096 + cg] = f2bf(acc[i][j][r] + bb);
        }
    }
}

// ---------------- kernel 4: scores + softmax -> P' = p + 63.875 ---------------------
__global__ __launch_bounds__(64) void scores(const unsigned short* __restrict__ Q,
                                             const unsigned short* __restrict__ K,
                                             float* __restrict__ P)
{
    __shared__ __align__(16) unsigned short qs[8 * 520];
    __shared__ __align__(16) unsigned short ks[8 * 520];
    const int r = blockIdx.x;        // b*512 + l
    const int lane = threadIdx.x;    // 64
    const unsigned short* qrow = Q + (size_t)r * 4096;
    const unsigned short* krow = K + (size_t)r * 4096;
    #pragma unroll
    for (int m = 0; m < 8; ++m) {
        *(uint4*)(&qs[m * 520 + lane * 8]) = *(const uint4*)(qrow + m * 512 + lane * 8);
        *(uint4*)(&ks[m * 520 + lane * 8]) = *(const uint4*)(krow + m * 512 + lane * 8);
    }
    __syncthreads();

    const int h = lane >> 3, g = lane & 7;
    const unsigned short* qh = &qs[h * 520];
    const unsigned short* kg = &ks[g * 520];
    float dot = 0.f;
    #pragma unroll 4
    for (int m = 0; m < 64; ++m) {
        uint4 qa = *(const uint4*)(qh + m * 8);
        uint4 ka = *(const uint4*)(kg + m * 8);
        dot += bflo(qa.x) * bflo(ka.x) + bfhi(qa.x) * bfhi(ka.x);
        dot += bflo(qa.y) * bflo(ka.y) + bfhi(qa.y) * bfhi(ka.y);
        dot += bflo(qa.z) * bflo(ka.z) + bfhi(qa.z) * bfhi(ka.z);
        dot += bflo(qa.w) * bflo(ka.w) + bfhi(qa.w) * bfhi(ka.w);
    }
    float s = dot * 0.04419417382415922f;   // 1/sqrt(512)
    float mx = s;
    mx = fmaxf(mx, __shfl_xor(mx, 1));
    mx = fmaxf(mx, __shfl_xor(mx, 2));
    mx = fmaxf(mx, __shfl_xor(mx, 4));
    float e = __expf(s - mx);
    float sm = e;
    sm += __shfl_xor(sm, 1);
    sm += __shfl_xor(sm, 2);
    sm += __shfl_xor(sm, 4);
    P[(size_t)r * 64 + lane] = e / sm + 63.875f;   // fold uniform part into P
}

// ---------------- kernel 5: c[b,hg] = sum_l P' ---------------------------------------
__global__ __launch_bounds__(256) void pbkern(const float* __restrict__ P,
                                              float* __restrict__ c)
{
    __shared__ float red[256];
    const int b = blockIdx.x, tid = threadIdx.x;
    const int hg = tid & 63, q = tid >> 6;
    float s = 0.f;
    for (int l = 0; l < 128; ++l) s += P[((size_t)b * 512 + q * 128 + l) * 64 + hg];
    red[tid] = s;
    __syncthreads();
    if (q == 0) c[b * 64 + hg] = red[hg] + red[64 + hg] + red[128 + hg] + red[192 + hg];
}

// ---------------- kernel 6: ypart[lc,b,hg,d] = sum_{l in chunk} P' * Xv --------------
__global__ __launch_bounds__(256) void ykern(const float* __restrict__ P,
                                             const float* __restrict__ Xv,
                                             float* __restrict__ ypart)
{
    __shared__ float Pl[128 * 64];
    __shared__ float Xl[128 * 64];
    const int b = blockIdx.x, dt = blockIdx.y, lc = blockIdx.z;
    const int tid = threadIdx.x;
    const int tm = tid & 15, te = tid >> 4;

    // load P chunk [128 l][64 hg] (contiguous) and Xv chunk [128 l][64 d]
    const float* Pg = P + ((size_t)b * 512 + lc * 128) * 64;
    #pragma unroll
    for (int i = 0; i < 8; ++i)
        *(float4*)&Pl[(i * 256 + tid) * 4] = *(const float4*)(Pg + (size_t)(i * 256 + tid) * 4);
    const float* Xg = Xv + ((size_t)b * 512 + lc * 128) * 512 + dt * 64;
    #pragma unroll
    for (int i = 0; i < 8; ++i) {
        int flat = i * 256 + tid;            // 2048 float4 = 128 rows x 16
        int r = flat >> 4, q = flat & 15;
        *(float4*)&Xl[r * 64 + q * 4] = *(const float4*)(Xg + (size_t)r * 512 + q * 4);
    }
    __syncthreads();

    float4 acc[4];
    #pragma unroll
    for (int i = 0; i < 4; ++i) acc[i] = make_float4(0.f, 0.f, 0.f, 0.f);

    for (int l = 0; l < 128; ++l) {
        float4 pv = *(const float4*)&Pl[l * 64 + tm * 4];
        float4 xv = *(const float4*)&Xl[l * 64 + te * 4];
        acc[0].x += pv.x * xv.x; acc[0].y += pv.x * xv.y; acc[0].z += pv.x * xv.z; acc[0].w += pv.x * xv.w;
        acc[1].x += pv.y * xv.x; acc[1].y += pv.y * xv.y; acc[1].z += pv.y * xv.z; acc[1].w += pv.y * xv.w;
        acc[2].x += pv.z * xv.x; acc[2].y += pv.z * xv.y; acc[2].z += pv.z * xv.z; acc[2].w += pv.z * xv.w;
        acc[3].x += pv.w * xv.x; acc[3].y += pv.w * xv.y; acc[3].z += pv.w * xv.z; acc[3].w += pv.w * xv.w;
    }
    // ypart[lc][b][hg][512]; hg = tm*4+i, d = dt*64 + te*4
    #pragma unroll
    for (int i = 0; i < 4; ++i)
        *(float4*)&ypart[(((size_t)lc * 8 + b) * 64 + tm * 4 + i) * 512 + dt * 64 + te * 4] = acc[i];
}

// ---------------- kernel 7: Y = sum_lc ypart ------------------------------------------
__global__ void yreduce(const float* __restrict__ ypart, float* __restrict__ Y)
{
    int fi = (blockIdx.x * 256 + threadIdx.x) * 4;   // 262144 floats
    float4 s = *(const float4*)(ypart + fi);
    #pragma unroll
    for (int lc = 1; lc < 4; ++lc) {
        float4 t = *(const float4*)(ypart + (size_t)lc * 262144 + fi);
        s.x += t.x; s.y += t.y; s.z += t.z; s.w += t.w;
    }
    *(float4*)(Y + fi) = s;
}

// ---------------- kernel 8: split-K vgemm: partial[kc,bh,e] --------------------------
// A2[bh, g*512+d] = Y[b*64 + h*8 + g][d];  B2[g*512+d, e] = Wv[d][g*512+e]
// k-chunk kc: g = kc>>3, d0 = (kc&7)*64.  e-tile et: e0 = et*64.
__global__ __launch_bounds__(256) void vgemm(const float* __restrict__ Y,
                                             const float* __restrict__ Wv,
                                             float* __restrict__ partial)
{
    __shared__ float Al[64 * 64];   // [bh][d], granule-XOR swizzled: gr' = dq ^ (bh>>2)
    __shared__ float Bl[64 * 64];   // [kk][e] linear
    const int et = blockIdx.x, kc = blockIdx.y;
    const int g = kc >> 3, d0 = (kc & 7) * 64, e0 = et * 64;
    const int tid = threadIdx.x;
    const int tm = tid & 15, te = tid >> 4;

    #pragma unroll
    for (int i = 0; i < 4; ++i) {
        int flat = i * 256 + tid;             // 1024 float4
        int bh = flat >> 4, dq = flat & 15;
        int yrow = (bh >> 3) * 64 + (bh & 7) * 8 + g;
        float4 v = *(const float4*)(Y + (size_t)yrow * 512 + d0 + dq * 4);
        *(float4*)&Al[bh * 64 + ((dq ^ (bh >> 2)) << 2)] = v;
    }
    #pragma unroll
    for (int i = 0; i < 4; ++i) {
        int flat = i * 256 + tid;
        int kk = flat >> 4, eq = flat & 15;
        *(float4*)&Bl[kk * 64 + eq * 4] =
            *(const float4*)(Wv + (size_t)(d0 + kk) * 4096 + g * 512 + e0 + eq * 4);
    }
    __syncthreads();

    float4 acc[4];
    #pragma unroll
    for (int j = 0; j < 4; ++j) acc[j] = make_float4(0.f, 0.f, 0.f, 0.f);

    for (int k = 0; k < 64; ++k) {
        float4 b4 = *(const float4*)&Bl[k * 64 + te * 4];
        const int gcol = (((k >> 2) ^ tm) << 2) + (k & 3);
        #pragma unroll
        for (int j = 0; j < 4; ++j) {
            float a = Al[(tm * 4 + j) * 64 + gcol];
            acc[j].x += a * b4.x; acc[j].y += a * b4.y;
            acc[j].z += a * b4.z; acc[j].w += a * b4.w;
        }
    }
    #pragma unroll
    for (int j = 0; j < 4; ++j)
        *(float4*)&partial[(size_t)kc * 32768 + (tm * 4 + j) * 512 + e0 + te * 4] = acc[j];
}

// ---------------- kernel 9: out = sum_kc partial + sum_g c*bv ------------------------
__global__ void finalize(const float* __restrict__ partial, const float* __restrict__ c,
                         const float* __restrict__ bv, float* __restrict__ out)
{
    int i = blockIdx.x * blockDim.x + threadIdx.x;  // 32768
    int b = i >> 12, h = (i >> 9) & 7, e = i & 511;
    float s = 0.f;
    #pragma unroll
    for (int kc = 0; kc < 64; ++kc) s += partial[(size_t)kc * 32768 + i];
    float bt = 0.f;
    #pragma unroll
    for (int g = 0; g < 8; ++g) bt += c[b * 64 + h * 8 + g] * bv[g * 512 + e];
    out[i] = s + bt;
}

extern "C" void kernel_launch(void* const* d_in, const int* in_sizes, int n_in,
                              void* d_out, int out_size, void* d_ws, size_t ws_size,
                              hipStream_t stream)
{
    const float* queries = (const float*)d_in[0];
    const float* keys    = (const float*)d_in[1];
    const float* values  = (const float*)d_in[2];
    const float* Wq      = (const float*)d_in[3];
    const float* bq      = (const float*)d_in[4];
    const float* Wk      = (const float*)d_in[5];
    const float* bk      = (const float*)d_in[6];
    const float* Wv      = (const float*)d_in[7];
    const float* bv      = (const float*)d_in[8];

    unsigned short* xq  = (unsigned short*)d_ws;
    unsigned short* xk  = xq  + (1u << 21);
    unsigned short* wtq = xk  + (1u << 21);
    unsigned short* wtk = wtq + (1u << 21);
    unsigned short* Q   = wtk + (1u << 21);
    unsigned short* Kb  = Q   + (1u << 24);
    float* P     = (float*)(Kb + (1u << 24));
    float* c     = P + 262144;
    float* ypart = c + 512;
    float* Y     = ypart + 1048576;
    float* part  = Y + 262144;

    convert_x<<<dim3(2048, 1, 2), 256, 0, stream>>>(queries, keys, xq, xk, 2097152);
    transpose_w<<<dim3(128, 16, 2), dim3(32, 8), 0, stream>>>(Wq, Wk, wtq, wtk);
    gemm_bt<<<dim3(32, 32, 2), 256, 0, stream>>>(xq, xk, wtq, wtk, bq, bk, Q, Kb);
    scores<<<dim3(4096), 64, 0, stream>>>(Q, Kb, P);
    pbkern<<<dim3(8), 256, 0, stream>>>(P, c);
    ykern<<<dim3(8, 8, 4), 256, 0, stream>>>(P, values, ypart);
    yreduce<<<dim3(256), 256, 0, stream>>>(ypart, Y);
    vgemm<<<dim3(8, 64), 256, 0, stream>>>(Y, Wv, part);
    finalize<<<dim3(128), 256, 0, stream>>>(part, c, bv, (float*)d_out);
}